// Round 1
// baseline (397.981 us; speedup 1.0000x reference)
//
#include <hip/hip_runtime.h>
#include <math.h>

#define B_DIM 1024
#define L_DIM 200
#define D_DIM 128

// ---------------------------------------------------------------------------
// K1: g0[b,:] = sum_l item_embedding[items[b,l], :]   (+ zero t and g)
// One block per b. 256 threads = 8 groups x 32 lanes; each lane reads float4.
// ---------------------------------------------------------------------------
__global__ __launch_bounds__(256) void k_gather(
    const float* __restrict__ emb,
    const int* __restrict__ items,
    float* __restrict__ g0,
    float* __restrict__ t,
    float* __restrict__ g) {
  const int b = blockIdx.x;
  const int tid = threadIdx.x;

  // zero the split-K accumulation buffers (ws is poisoned with 0xAA)
  if (tid < D_DIM) {
    t[b * D_DIM + tid] = 0.f;
    g[b * D_DIM + tid] = 0.f;
  }

  __shared__ int sidx[L_DIM];
  if (tid < L_DIM) sidx[tid] = items[b * L_DIM + tid];
  __syncthreads();

  const int grp = tid >> 5;   // 0..7
  const int lane = tid & 31;  // 0..31, each owns a float4 (4 of 128 cols)

  float4 acc = make_float4(0.f, 0.f, 0.f, 0.f);
  for (int l = grp; l < L_DIM; l += 8) {
    const float4* p =
        reinterpret_cast<const float4*>(emb + (long long)sidx[l] * D_DIM) + lane;
    float4 v = *p;
    acc.x += v.x; acc.y += v.y; acc.z += v.z; acc.w += v.w;
  }

  __shared__ float4 red[8][32];
  red[grp][lane] = acc;
  __syncthreads();

  if (tid < D_DIM) {
    float s = 0.f;
#pragma unroll
    for (int j = 0; j < 8; ++j) {
      const float* rp = reinterpret_cast<const float*>(&red[j][0]);
      s += rp[tid];
    }
    g0[b * D_DIM + tid] = s;
  }
}

// ---------------------------------------------------------------------------
// K2/K3: C[1024,128] += A[1024,1024] @ Bm[1024,128]   (f32, split-K atomics)
// grid = (16 row-tiles of 64) x (16 K-chunks of 64); block = 256 threads.
// Each thread computes an 8x4 micro-tile; per-k: 2 broadcast A reads + 1
// float4 B read feeding 32 FMAs.
// ---------------------------------------------------------------------------
__global__ __launch_bounds__(256) void k_matmul_splitk(
    const float* __restrict__ A,   // [1024][1024]
    const float* __restrict__ Bm,  // [1024][128]
    float* __restrict__ C) {       // [1024][128] (pre-zeroed)
  const int rt = blockIdx.x;  // row tile 0..15
  const int kc = blockIdx.y;  // K chunk  0..15
  const int tid = threadIdx.x;

  __shared__ float As[64][68];   // [r][k], padded row stride (272B, 16B-aligned)
  __shared__ float Bs[64][128];  // [k][c]

  // load A tile: 64x64 floats, 4 float4 per thread, coalesced along k
#pragma unroll
  for (int i = 0; i < 4; ++i) {
    int tt = tid + i * 256;
    int r = tt >> 4;             // 0..63
    int k4 = (tt & 15) << 2;     // 0..60
    float4 v = *reinterpret_cast<const float4*>(
        A + (long long)(rt * 64 + r) * 1024 + kc * 64 + k4);
    *reinterpret_cast<float4*>(&As[r][k4]) = v;
  }
  // load B tile: 64x128 floats, 8 float4 per thread, fully coalesced rows
#pragma unroll
  for (int i = 0; i < 8; ++i) {
    int tt = tid + i * 256;
    int k = tt >> 5;             // 0..63
    int c4 = (tt & 31) << 2;     // 0..124
    float4 v = *reinterpret_cast<const float4*>(
        Bm + (long long)(kc * 64 + k) * 128 + c4);
    *reinterpret_cast<float4*>(&Bs[k][c4]) = v;
  }
  __syncthreads();

  const int tr = tid >> 5;       // 0..7  -> rows r0..r0+7
  const int tc = tid & 31;       // 0..31 -> cols c0..c0+3
  const int r0 = tr * 8;
  const int c0 = tc * 4;

  float acc[8][4];
#pragma unroll
  for (int i = 0; i < 8; ++i)
#pragma unroll
    for (int j = 0; j < 4; ++j) acc[i][j] = 0.f;

#pragma unroll 4
  for (int k = 0; k < 64; ++k) {
    float4 bv = *reinterpret_cast<const float4*>(&Bs[k][c0]);
#pragma unroll
    for (int i = 0; i < 8; ++i) {
      float a = As[r0 + i][k];
      acc[i][0] = fmaf(a, bv.x, acc[i][0]);
      acc[i][1] = fmaf(a, bv.y, acc[i][1]);
      acc[i][2] = fmaf(a, bv.z, acc[i][2]);
      acc[i][3] = fmaf(a, bv.w, acc[i][3]);
    }
  }

#pragma unroll
  for (int i = 0; i < 8; ++i) {
    int row = rt * 64 + r0 + i;
#pragma unroll
    for (int j = 0; j < 4; ++j) {
      atomicAdd(&C[row * 128 + c0 + j], acc[i][j]);
    }
  }
}

// ---------------------------------------------------------------------------
// K4: out[b,:] = selu(g[b,:]) / ||selu(g[b,:])||_2
// ---------------------------------------------------------------------------
__global__ __launch_bounds__(128) void k_epilogue(const float* __restrict__ g,
                                                  float* __restrict__ out) {
  const int b = blockIdx.x;
  const int tid = threadIdx.x;
  const float sc = 1.0507009873554805f;
  const float al = 1.6732632423543772f;

  float v = g[b * D_DIM + tid];
  float y = v > 0.f ? sc * v : sc * al * expm1f(v);

  float ss = y * y;
#pragma unroll
  for (int o = 1; o < 64; o <<= 1) ss += __shfl_xor(ss, o, 64);

  __shared__ float wsum[2];
  if ((tid & 63) == 0) wsum[tid >> 6] = ss;
  __syncthreads();
  float tot = wsum[0] + wsum[1];

  out[b * D_DIM + tid] = y * (1.f / sqrtf(tot));
}

// ---------------------------------------------------------------------------
extern "C" void kernel_launch(void* const* d_in, const int* in_sizes, int n_in,
                              void* d_out, int out_size, void* d_ws,
                              size_t ws_size, hipStream_t stream) {
  const float* emb   = (const float*)d_in[0];  // [500000,128]
  const int*   items = (const int*)d_in[1];    // [1024,200]
  const float* A     = (const float*)d_in[2];  // [1024,1024]
  const float* D     = (const float*)d_in[3];  // [1024,1024]
  // d_in[4..10] (intention_embedding, atten_*, alpha_*) are mathematically
  // irrelevant: scores are constant along L, so entmax is uniform and
  // c = g exactly.
  float* out = (float*)d_out;                  // [1024,128] f32

  float* g0 = (float*)d_ws;          // [1024,128]
  float* t  = g0 + B_DIM * D_DIM;    // [1024,128]
  float* g  = t + B_DIM * D_DIM;     // [1024,128]

  k_gather<<<B_DIM, 256, 0, stream>>>(emb, items, g0, t, g);

  dim3 grid2(16, 16);
  k_matmul_splitk<<<grid2, 256, 0, stream>>>(A, g0, t);   // t = A @ g0
  k_matmul_splitk<<<grid2, 256, 0, stream>>>(D, t, g);    // g = D @ t

  k_epilogue<<<B_DIM, 128, 0, stream>>>(g, out);
}

// Round 2
// 344.568 us; speedup vs baseline: 1.1550x; 1.1550x over previous
//
#include <hip/hip_runtime.h>
#include <math.h>

#define B_DIM 1024
#define L_DIM 200
#define D_DIM 128
#define KC_N 16    // split-K chunks
#define KCHUNK 64  // K per chunk
#define RT_N 32    // row tiles
#define RROWS 32   // rows per tile

// ---------------------------------------------------------------------------
// K1: g0[b,:] = sum_l item_embedding[items[b,l], :]
// One block per b. 256 threads = 8 groups x 32 lanes; each lane reads float4.
// ---------------------------------------------------------------------------
__global__ __launch_bounds__(256) void k_gather(
    const float* __restrict__ emb,
    const int* __restrict__ items,
    float* __restrict__ g0) {
  const int b = blockIdx.x;
  const int tid = threadIdx.x;

  __shared__ int sidx[L_DIM];
  if (tid < L_DIM) sidx[tid] = items[b * L_DIM + tid];
  __syncthreads();

  const int grp = tid >> 5;   // 0..7
  const int lane = tid & 31;  // 0..31, each owns a float4 (4 of 128 cols)

  float4 acc = make_float4(0.f, 0.f, 0.f, 0.f);
  for (int l = grp; l < L_DIM; l += 8) {
    const float4* p =
        reinterpret_cast<const float4*>(emb + (long long)sidx[l] * D_DIM) + lane;
    float4 v = *p;
    acc.x += v.x; acc.y += v.y; acc.z += v.z; acc.w += v.w;
  }

  __shared__ float4 red[8][32];
  red[grp][lane] = acc;
  __syncthreads();

  if (tid < D_DIM) {
    float s = 0.f;
#pragma unroll
    for (int j = 0; j < 8; ++j) {
      const float* rp = reinterpret_cast<const float*>(&red[j][0]);
      s += rp[tid];
    }
    g0[b * D_DIM + tid] = s;
  }
}

// ---------------------------------------------------------------------------
// K2/K4: P[kc][rows][128] = M[rows][kc-chunk] @ Bm[kc-chunk][128]
// No atomics: each (rt,kc) block writes its own contention-free partial.
// grid = (32 row-tiles of 32) x (16 K-chunks of 64); block = 256 (2 blk/CU).
// Thread computes a 4x4 micro-tile: per k, 4 broadcast A reads + 1
// conflict-free ds_read_b128 of B + 16 FMAs.
// ---------------------------------------------------------------------------
__global__ __launch_bounds__(256) void k_mm_partial(
    const float* __restrict__ M,   // [1024][1024]
    const float* __restrict__ Bm,  // [1024][128]
    float* __restrict__ P) {       // [KC_N][1024][128]
  const int rt = blockIdx.x;
  const int kc = blockIdx.y;
  const int tid = threadIdx.x;

  __shared__ float As[RROWS][KCHUNK + 4];  // padded: 32 x 68
  __shared__ float Bs[KCHUNK][D_DIM];      // 64 x 128

  // A tile: 32 rows x 64 k = 512 float4, 2 per thread, coalesced along k
#pragma unroll
  for (int i = 0; i < 2; ++i) {
    int tt = tid + i * 256;
    int r = tt >> 4;           // 0..31 (16 float4 per row)
    int k4 = (tt & 15) << 2;   // 0..60
    float4 v = *reinterpret_cast<const float4*>(
        M + (long long)(rt * RROWS + r) * B_DIM + kc * KCHUNK + k4);
    *reinterpret_cast<float4*>(&As[r][k4]) = v;
  }
  // B tile: 64 k x 128 c = 2048 float4, 8 per thread, fully coalesced
#pragma unroll
  for (int i = 0; i < 8; ++i) {
    int tt = tid + i * 256;
    int k = tt >> 5;           // 0..63
    int c4 = (tt & 31) << 2;   // 0..124
    float4 v = *reinterpret_cast<const float4*>(
        Bm + (long long)(kc * KCHUNK + k) * D_DIM + c4);
    *reinterpret_cast<float4*>(&Bs[k][c4]) = v;
  }
  __syncthreads();

  const int rr = tid >> 5;   // 0..7  -> rows 4rr..4rr+3
  const int cc = tid & 31;   // 0..31 -> cols 4cc..4cc+3
  const int r0 = rr * 4;
  const int c0 = cc * 4;

  float acc[4][4];
#pragma unroll
  for (int i = 0; i < 4; ++i)
#pragma unroll
    for (int j = 0; j < 4; ++j) acc[i][j] = 0.f;

#pragma unroll 4
  for (int k = 0; k < KCHUNK; ++k) {
    float4 bv = *reinterpret_cast<const float4*>(&Bs[k][c0]);
    float a0 = As[r0 + 0][k];
    float a1 = As[r0 + 1][k];
    float a2 = As[r0 + 2][k];
    float a3 = As[r0 + 3][k];
    acc[0][0] = fmaf(a0, bv.x, acc[0][0]); acc[0][1] = fmaf(a0, bv.y, acc[0][1]);
    acc[0][2] = fmaf(a0, bv.z, acc[0][2]); acc[0][3] = fmaf(a0, bv.w, acc[0][3]);
    acc[1][0] = fmaf(a1, bv.x, acc[1][0]); acc[1][1] = fmaf(a1, bv.y, acc[1][1]);
    acc[1][2] = fmaf(a1, bv.z, acc[1][2]); acc[1][3] = fmaf(a1, bv.w, acc[1][3]);
    acc[2][0] = fmaf(a2, bv.x, acc[2][0]); acc[2][1] = fmaf(a2, bv.y, acc[2][1]);
    acc[2][2] = fmaf(a2, bv.z, acc[2][2]); acc[2][3] = fmaf(a2, bv.w, acc[2][3]);
    acc[3][0] = fmaf(a3, bv.x, acc[3][0]); acc[3][1] = fmaf(a3, bv.y, acc[3][1]);
    acc[3][2] = fmaf(a3, bv.z, acc[3][2]); acc[3][3] = fmaf(a3, bv.w, acc[3][3]);
  }

#pragma unroll
  for (int i = 0; i < 4; ++i) {
    int row = rt * RROWS + r0 + i;
    *reinterpret_cast<float4*>(
        &P[((long long)kc * B_DIM + row) * D_DIM + c0]) =
        make_float4(acc[i][0], acc[i][1], acc[i][2], acc[i][3]);
  }
}

// ---------------------------------------------------------------------------
// K3: T[b,c] = sum_kc P[kc][b][c]
// ---------------------------------------------------------------------------
__global__ __launch_bounds__(128) void k_reduce(const float* __restrict__ P,
                                                float* __restrict__ T) {
  const int b = blockIdx.x;
  const int c = threadIdx.x;
  float s = 0.f;
#pragma unroll
  for (int kc = 0; kc < KC_N; ++kc)
    s += P[((long long)kc * B_DIM + b) * D_DIM + c];
  T[b * D_DIM + c] = s;
}

// ---------------------------------------------------------------------------
// K5: out[b,:] = selu(sum_kc P[kc][b,:]) then L2-normalize the row
// ---------------------------------------------------------------------------
__global__ __launch_bounds__(128) void k_reduce_selu_norm(
    const float* __restrict__ P, float* __restrict__ out) {
  const int b = blockIdx.x;
  const int c = threadIdx.x;
  float s = 0.f;
#pragma unroll
  for (int kc = 0; kc < KC_N; ++kc)
    s += P[((long long)kc * B_DIM + b) * D_DIM + c];

  const float sc = 1.0507009873554805f;
  const float al = 1.6732632423543772f;
  float y = s > 0.f ? sc * s : sc * al * expm1f(s);

  float ss = y * y;
#pragma unroll
  for (int o = 1; o < 64; o <<= 1) ss += __shfl_xor(ss, o, 64);

  __shared__ float wsum[2];
  if ((c & 63) == 0) wsum[c >> 6] = ss;
  __syncthreads();
  float tot = wsum[0] + wsum[1];

  out[b * D_DIM + c] = y * (1.f / sqrtf(tot));
}

// ---------------------------------------------------------------------------
extern "C" void kernel_launch(void* const* d_in, const int* in_sizes, int n_in,
                              void* d_out, int out_size, void* d_ws,
                              size_t ws_size, hipStream_t stream) {
  const float* emb   = (const float*)d_in[0];  // [500000,128]
  const int*   items = (const int*)d_in[1];    // [1024,200]
  const float* A     = (const float*)d_in[2];  // [1024,1024]
  const float* D     = (const float*)d_in[3];  // [1024,1024]
  // d_in[4..10] are mathematically irrelevant: scores are constant along L,
  // so entmax is uniform, p sums to 1, and c = g exactly.
  float* out = (float*)d_out;                  // [1024,128] f32

  float* g0 = (float*)d_ws;                              // [1024][128]
  float* pA = g0 + B_DIM * D_DIM;                        // [16][1024][128]
  float* t  = pA + (long long)KC_N * B_DIM * D_DIM;      // [1024][128]
  float* pB = t + B_DIM * D_DIM;                         // [16][1024][128]

  k_gather<<<B_DIM, 256, 0, stream>>>(emb, items, g0);

  dim3 gmm(RT_N, KC_N);
  k_mm_partial<<<gmm, 256, 0, stream>>>(A, g0, pA);      // pA = A @ g0 (split-K)
  k_reduce<<<B_DIM, 128, 0, stream>>>(pA, t);            // t = sum(pA)
  k_mm_partial<<<gmm, 256, 0, stream>>>(D, t, pB);       // pB = D @ t (split-K)
  k_reduce_selu_norm<<<B_DIM, 128, 0, stream>>>(pB, out);
}